// Round 6
// baseline (458.904 us; speedup 1.0000x reference)
//
#include <hip/hip_runtime.h>

// ---------------------------------------------------------------------------
// BiasCrossAttentionFusion on gfx950 — round 5.
//   R5 vs R4 (456us, flash 91us @ VALU 43 / MFMA 23 / occ 19%, 7.3M LDS cf):
//   * k_flash: XOR-swizzled stride-64 LDS tiles (conflict-free ds_read_b128,
//     was 8-way at stride-72; LDS 46->40KB = 4 blocks/CU), KV-split x2
//     (grid 1024) with f32 partials + k_combine, exp2-folded softmax.
//   * wo/ff2: 128x64-tile GEMM, 512 blocks (were 256 blocks = 1 block/CU).
//   * qkv/ff1: __launch_bounds__(256,3) for 3 blocks/CU (m97 occupancy).
// ---------------------------------------------------------------------------

typedef __bf16 bf16x8 __attribute__((ext_vector_type(8)));
typedef float  f32x4  __attribute__((ext_vector_type(4)));

__device__ inline f32x4 mfma16(bf16x8 a, bf16x8 b, f32x4 c) {
  return __builtin_amdgcn_mfma_f32_16x16x32_bf16(a, b, c, 0, 0, 0);
}

__device__ inline void glds16(const void* g, void* l) {
  __builtin_amdgcn_global_load_lds(
      (const __attribute__((address_space(1))) void*)g,
      (__attribute__((address_space(3))) void*)l, 16, 0, 0);
}

// swizzled LDS offset for a 64-elem bf16 row: chunk (16B) index XOR (row&7)
__device__ inline int swz(int row, int col) {
  return row * 64 + ((((col >> 3) ^ (row & 7)) << 3) | (col & 7));
}

#define DB 1024
#define DH 16
#define DHD 64
#define DP 64
#define NB 4
#define NN 1024
#define NM 2048

// ---------------- all weight transposes (f32 [K,O] -> bf16 [O,K]) ----------
__global__ __launch_bounds__(256) void k_transpose_all(
    const float* __restrict__ w0, const float* __restrict__ w1,
    const float* __restrict__ w2, const float* __restrict__ w3,
    const float* __restrict__ f1, const float* __restrict__ f2,
    const float* __restrict__ g0, const float* __restrict__ g1,
    __bf16* __restrict__ o0, __bf16* __restrict__ o1,
    __bf16* __restrict__ o2, __bf16* __restrict__ o3,
    __bf16* __restrict__ of1, __bf16* __restrict__ of2,
    __bf16* __restrict__ og0, __bf16* __restrict__ og1) {
  __shared__ float tile[32][33];
  int id = blockIdx.x;
  const float* in;
  __bf16* out;
  int K, O, x, y;
  if (id < 4096) {
    int mi = id >> 10, r = id & 1023;
    in = mi == 0 ? w0 : mi == 1 ? w1 : mi == 2 ? w2 : w3;
    out = mi == 0 ? o0 : mi == 1 ? o1 : mi == 2 ? o2 : o3;
    K = 1024; O = 1024; x = r & 31; y = r >> 5;
  } else if (id < 6144) {
    int r = id - 4096; in = f1; out = of1; K = 1024; O = 2048; x = r & 63; y = r >> 6;
  } else if (id < 8192) {
    int r = id - 6144; in = f2; out = of2; K = 2048; O = 1024; x = r & 31; y = r >> 5;
  } else if (id < 8256) {
    int r = id - 8192; in = g0; out = og0; K = 1024; O = 64; x = r & 1; y = r >> 1;
  } else {
    int r = id - 8256; in = g1; out = og1; K = 1024; O = 64; x = r & 1; y = r >> 1;
  }
  int k0 = y * 32, o0c = x * 32;
  int tx = threadIdx.x & 31, ty = threadIdx.x >> 5;
#pragma unroll
  for (int r = ty; r < 32; r += 8)
    tile[r][tx] = in[(size_t)(k0 + r) * O + (o0c + tx)];
  __syncthreads();
#pragma unroll
  for (int r = ty; r < 32; r += 8)
    out[(size_t)(o0c + r) * K + (k0 + tx)] = (__bf16)tile[tx][r];
}

// ---------------- LayerNorm D=1024, one block/row, bf16 out ----------------
__device__ inline void ln_body(const float* __restrict__ x,
                               const float* __restrict__ g,
                               const float* __restrict__ bb,
                               __bf16* __restrict__ y, size_t row) {
  int t = threadIdx.x;
  float4 v = ((const float4*)(x + row * 1024))[t];
  float s = v.x + v.y + v.z + v.w;
  float ss = v.x * v.x + v.y * v.y + v.z * v.z + v.w * v.w;
#pragma unroll
  for (int o = 32; o; o >>= 1) {
    s += __shfl_down(s, o, 64);
    ss += __shfl_down(ss, o, 64);
  }
  __shared__ float r1[4], r2[4];
  if ((t & 63) == 0) { r1[t >> 6] = s; r2[t >> 6] = ss; }
  __syncthreads();
  s = r1[0] + r1[1] + r1[2] + r1[3];
  ss = r2[0] + r2[1] + r2[2] + r2[3];
  float mu = s * (1.f / 1024.f);
  float rstd = rsqrtf(ss * (1.f / 1024.f) - mu * mu + 1e-5f);
  float4 gv = ((const float4*)g)[t];
  float4 bv = ((const float4*)bb)[t];
  __bf16* yr = y + row * 1024 + t * 4;
  yr[0] = (__bf16)((v.x - mu) * rstd * gv.x + bv.x);
  yr[1] = (__bf16)((v.y - mu) * rstd * gv.y + bv.y);
  yr[2] = (__bf16)((v.z - mu) * rstd * gv.z + bv.z);
  yr[3] = (__bf16)((v.w - mu) * rstd * gv.w + bv.w);
}

__global__ __launch_bounds__(256) void k_layernorm(
    const float* __restrict__ x, const float* __restrict__ g,
    const float* __restrict__ bb, __bf16* __restrict__ y) {
  ln_body(x, g, bb, y, blockIdx.x);
}

__global__ __launch_bounds__(256) void k_layernorm2(
    const float* __restrict__ x1, const float* __restrict__ g1,
    const float* __restrict__ b1, __bf16* __restrict__ y1,
    const float* __restrict__ x2, const float* __restrict__ g2,
    const float* __restrict__ b2, __bf16* __restrict__ y2) {
  int row = blockIdx.x;
  if (row < 4096) ln_body(x1, g1, b1, y1, row);
  else ln_body(x2, g2, b2, y2, row - 4096);
}

// ---------------- geo projections: q(128 blk) + kv(256 blk), 32x64 tiles ---
__global__ __launch_bounds__(256) void k_geo(
    const __bf16* __restrict__ qin, const __bf16* __restrict__ kvin,
    const __bf16* __restrict__ gqw, const __bf16* __restrict__ gkw,
    const float* __restrict__ gqb, const float* __restrict__ gkb,
    __bf16* __restrict__ geoq, __bf16* __restrict__ geok) {
  const int blk = blockIdx.x;
  const bool isq = blk < 128;
  const __bf16* A = isq ? qin : kvin;
  const __bf16* Bt = isq ? gqw : gkw;
  const float* bias = isq ? gqb : gkb;
  __bf16* C = isq ? geoq : geok;
  const int row0 = (isq ? blk : blk - 128) * 32;
  __shared__ __align__(16) __bf16 As[32][72], Bs[64][72];
  const int t = threadIdx.x, lane = t & 63, w = t >> 6;
  const int quad = lane >> 4, l15 = lane & 15;
  const int wr = w >> 1, wc = w & 1;
  const int sr = t >> 3, skc = (t & 7) * 8;
  const __bf16* aP = A + (size_t)(row0 + sr) * 1024 + skc;
  const __bf16* bP0 = Bt + (size_t)sr * 1024 + skc;
  const __bf16* bP1 = Bt + (size_t)(sr + 32) * 1024 + skc;
  bf16x8 av = *(const bf16x8*)aP;
  bf16x8 bv0 = *(const bf16x8*)bP0;
  bf16x8 bv1 = *(const bf16x8*)bP1;
  f32x4 acc[2] = {};
  for (int k0 = 0; k0 < 1024; k0 += 64) {
    __syncthreads();
    *(bf16x8*)&As[sr][skc] = av;
    *(bf16x8*)&Bs[sr][skc] = bv0;
    *(bf16x8*)&Bs[sr + 32][skc] = bv1;
    __syncthreads();
    if (k0 + 64 < 1024) {
      av = *(const bf16x8*)(aP + k0 + 64);
      bv0 = *(const bf16x8*)(bP0 + k0 + 64);
      bv1 = *(const bf16x8*)(bP1 + k0 + 64);
    }
#pragma unroll
    for (int ks = 0; ks < 2; ks++) {
      bf16x8 af = *(const bf16x8*)&As[wr * 16 + l15][ks * 32 + quad * 8];
#pragma unroll
      for (int ct = 0; ct < 2; ct++) {
        bf16x8 bfr = *(const bf16x8*)&Bs[wc * 32 + ct * 16 + l15][ks * 32 + quad * 8];
        acc[ct] = mfma16(af, bfr, acc[ct]);
      }
    }
  }
#pragma unroll
  for (int ct = 0; ct < 2; ct++) {
    int col = wc * 32 + ct * 16 + l15;
    float bc = bias[col];
#pragma unroll
    for (int i = 0; i < 4; i++) {
      int row = row0 + wr * 16 + quad * 4 + i;
      C[(size_t)row * 64 + col] = (__bf16)(acc[ct][i] + bc);
    }
  }
}

// ---------------- l2 norms, phase 1: column sum-of-squares -----------------
__global__ __launch_bounds__(256) void k_l2sum(
    const __bf16* __restrict__ gq, const __bf16* __restrict__ gk,
    float* __restrict__ sums) {
  int chunk = blockIdx.x, b = blockIdx.y, z = blockIdx.z;
  if (z == 0 && chunk >= 8) return;
  const __bf16* src = z ? gk : gq;
  int rows = z ? 2048 : 1024;
  const unsigned* base = (const unsigned*)(src + (size_t)b * rows * 64) + chunk * 128 * 32;
  int t = threadIdx.x, c = t & 31, ro = t >> 5;
  float s0 = 0.f, s1 = 0.f;
  for (int r = ro; r < 128; r += 8) {
    unsigned u = base[r * 32 + c];
    float f0 = __uint_as_float(u << 16);
    float f1 = __uint_as_float(u & 0xffff0000u);
    s0 += f0 * f0;
    s1 += f1 * f1;
  }
  __shared__ float ls[64];
  if (t < 64) ls[t] = 0.f;
  __syncthreads();
  atomicAdd(&ls[c * 2], s0);
  atomicAdd(&ls[c * 2 + 1], s1);
  __syncthreads();
  if (t < 64) atomicAdd(&sums[z * 256 + b * 64 + t], ls[t]);
}

// ---------------- l2 phase 2: scale geo_k by 1/(||q_p||*||k_p||) -----------
__global__ __launch_bounds__(256) void k_l2scale(
    __bf16* __restrict__ gk, const float* __restrict__ sums) {
  int chunk = blockIdx.x, b = blockIdx.y;
  unsigned* base = (unsigned*)(gk + (size_t)b * 2048 * 64) + chunk * 128 * 32;
  int t = threadIdx.x, c = t & 31, ro = t >> 5;
  float sq0 = sums[b * 64 + c * 2], sq1 = sums[b * 64 + c * 2 + 1];
  float sk0 = sums[256 + b * 64 + c * 2], sk1 = sums[256 + b * 64 + c * 2 + 1];
  float m0 = 1.f / (fmaxf(sqrtf(sq0), 1e-12f) * fmaxf(sqrtf(sk0), 1e-12f));
  float m1 = 1.f / (fmaxf(sqrtf(sq1), 1e-12f) * fmaxf(sqrtf(sk1), 1e-12f));
  for (int r = ro; r < 128; r += 8) {
    unsigned u = base[r * 32 + c];
    float f0 = __uint_as_float(u << 16) * m0;
    float f1 = __uint_as_float(u & 0xffff0000u) * m1;
    unsigned short h0 = __builtin_bit_cast(unsigned short, (__bf16)f0);
    unsigned short h1 = __builtin_bit_cast(unsigned short, (__bf16)f1);
    base[r * 32 + c] = (unsigned)h0 | ((unsigned)h1 << 16);
  }
}

// ---------------- fused QKV: qb(256) + kb(512) + vtb(512) blocks -----------
__global__ __launch_bounds__(256, 3) void k_qkv(
    const __bf16* __restrict__ qin, const __bf16* __restrict__ kvin,
    const __bf16* __restrict__ twq, const __bf16* __restrict__ twk,
    const __bf16* __restrict__ twv, const float* __restrict__ qbias,
    const float* __restrict__ kbias, const float* __restrict__ vbias,
    __bf16* __restrict__ qb, __bf16* __restrict__ kb, __bf16* __restrict__ vtb) {
  int id = blockIdx.x;
  const __bf16 *A, *Bt;
  const float* bias;
  __bf16* C;
  int my, nx, Ndim;
  bool rowbias;
  if (id < 256) {
    A = qin; Bt = twq; bias = qbias; C = qb;
    nx = id & 7; my = id >> 3; Ndim = 1024; rowbias = false;
  } else if (id < 768) {
    id -= 256;
    A = kvin; Bt = twk; bias = kbias; C = kb;
    nx = id & 7; my = id >> 3; Ndim = 1024; rowbias = false;
  } else {
    id -= 768;
    A = twv; Bt = kvin; bias = vbias; C = vtb;
    nx = id & 63; my = id >> 6; Ndim = 8192; rowbias = true;
  }
  const int Kdim = 1024;
  __shared__ __align__(16) __bf16 As[128 * 32];
  __shared__ __align__(16) __bf16 Bs[128 * 32];
  const int m0 = my * 128, n0 = nx * 128;
  const int t = threadIdx.x, lane = t & 63, w = t >> 6;
  const int quad = lane >> 4, l15 = lane & 15;
  const int wr = w >> 1, wc = w & 1;
  const int srow = lane >> 2, scol = (lane & 3) * 8;
  const __bf16* aS0 = A + (size_t)(m0 + w * 32 + srow) * Kdim + scol;
  const __bf16* bS0 = Bt + (size_t)(n0 + w * 32 + srow) * Kdim + scol;
  const size_t K16 = (size_t)16 * Kdim;
  __bf16* lA0 = &As[(w * 32) * 32];
  __bf16* lB0 = &Bs[(w * 32) * 32];

  f32x4 acc[4][4] = {};
  for (int k0 = 0; k0 < Kdim; k0 += 32) {
    __syncthreads();
    glds16(aS0 + k0, lA0);
    glds16(aS0 + K16 + k0, lA0 + 16 * 32);
    glds16(bS0 + k0, lB0);
    glds16(bS0 + K16 + k0, lB0 + 16 * 32);
    __syncthreads();
    bf16x8 af[4], bg[4];
#pragma unroll
    for (int rt = 0; rt < 4; rt++)
      af[rt] = *(const bf16x8*)&As[(wr * 64 + rt * 16 + l15) * 32 + quad * 8];
#pragma unroll
    for (int ct = 0; ct < 4; ct++)
      bg[ct] = *(const bf16x8*)&Bs[(wc * 64 + ct * 16 + l15) * 32 + quad * 8];
#pragma unroll
    for (int rt = 0; rt < 4; rt++)
#pragma unroll
      for (int ct = 0; ct < 4; ct++)
        acc[rt][ct] = mfma16(af[rt], bg[ct], acc[rt][ct]);
  }
#pragma unroll
  for (int rt = 0; rt < 4; rt++) {
    int row = m0 + wr * 64 + rt * 16 + quad * 4;
#pragma unroll
    for (int ct = 0; ct < 4; ct++) {
      int col = n0 + wc * 64 + ct * 16 + l15;
      float bcol = rowbias ? 0.f : bias[col];
#pragma unroll
      for (int i = 0; i < 4; i++) {
        float vv = acc[rt][ct][i] + (rowbias ? bias[row + i] : bcol);
        C[(size_t)(row + i) * Ndim + col] = (__bf16)vv;
      }
    }
  }
}

// ---------------- big GEMM 128x128 (ff1: gelu epilogue) --------------------
__global__ __launch_bounds__(256, 3) void k_gemm128g(
    const __bf16* __restrict__ A, const __bf16* __restrict__ Bt,
    const float* __restrict__ bias, __bf16* __restrict__ Cout,
    int Ndim, int Kdim) {
  __shared__ __align__(16) __bf16 As[128 * 32];
  __shared__ __align__(16) __bf16 Bs[128 * 32];
  const int m0 = blockIdx.y * 128, n0 = blockIdx.x * 128;
  const int t = threadIdx.x, lane = t & 63, w = t >> 6;
  const int quad = lane >> 4, l15 = lane & 15;
  const int wr = w >> 1, wc = w & 1;
  const int srow = lane >> 2, scol = (lane & 3) * 8;
  const __bf16* aS0 = A + (size_t)(m0 + w * 32 + srow) * Kdim + scol;
  const __bf16* bS0 = Bt + (size_t)(n0 + w * 32 + srow) * Kdim + scol;
  const size_t K16 = (size_t)16 * Kdim;
  __bf16* lA0 = &As[(w * 32) * 32];
  __bf16* lB0 = &Bs[(w * 32) * 32];

  f32x4 acc[4][4] = {};
  for (int k0 = 0; k0 < Kdim; k0 += 32) {
    __syncthreads();
    glds16(aS0 + k0, lA0);
    glds16(aS0 + K16 + k0, lA0 + 16 * 32);
    glds16(bS0 + k0, lB0);
    glds16(bS0 + K16 + k0, lB0 + 16 * 32);
    __syncthreads();
    bf16x8 af[4], bg[4];
#pragma unroll
    for (int rt = 0; rt < 4; rt++)
      af[rt] = *(const bf16x8*)&As[(wr * 64 + rt * 16 + l15) * 32 + quad * 8];
#pragma unroll
    for (int ct = 0; ct < 4; ct++)
      bg[ct] = *(const bf16x8*)&Bs[(wc * 64 + ct * 16 + l15) * 32 + quad * 8];
#pragma unroll
    for (int rt = 0; rt < 4; rt++)
#pragma unroll
      for (int ct = 0; ct < 4; ct++)
        acc[rt][ct] = mfma16(af[rt], bg[ct], acc[rt][ct]);
  }
#pragma unroll
  for (int rt = 0; rt < 4; rt++) {
    int row = m0 + wr * 64 + rt * 16 + quad * 4;
#pragma unroll
    for (int ct = 0; ct < 4; ct++) {
      int col = n0 + wc * 64 + ct * 16 + l15;
      float bcol = bias[col];
#pragma unroll
      for (int i = 0; i < 4; i++) {
        float vv = acc[rt][ct][i] + bcol;
        Cout[(size_t)(row + i) * Ndim + col] =
            (__bf16)(0.5f * vv * (1.f + erff(vv * 0.70710678118f)));
      }
    }
  }
}

// ---------------- GEMM 128x64 tile (wo / ff2): +bias +resid -> f32 ---------
// 512 blocks for N=1024 outputs (vs 256 with 128x128 = 1 block/CU).
__global__ __launch_bounds__(256, 2) void k_gemmn64(
    const __bf16* __restrict__ A, const __bf16* __restrict__ Bt,
    const float* __restrict__ bias, const float* __restrict__ resid,
    float* __restrict__ Cout, int Ndim, int Kdim) {
  __shared__ __align__(16) __bf16 As[128 * 32];
  __shared__ __align__(16) __bf16 Bs[64 * 32];
  const int m0 = blockIdx.y * 128, n0 = blockIdx.x * 64;
  const int t = threadIdx.x, lane = t & 63, w = t >> 6;
  const int quad = lane >> 4, l15 = lane & 15;
  const int wr = w >> 1, wc = w & 1;
  const int srow = lane >> 2, scol = (lane & 3) * 8;
  const __bf16* aS0 = A + (size_t)(m0 + w * 32 + srow) * Kdim + scol;
  const __bf16* bS0 = Bt + (size_t)(n0 + w * 16 + srow) * Kdim + scol;  // 16 rows/wave
  const size_t K16 = (size_t)16 * Kdim;
  __bf16* lA0 = &As[(w * 32) * 32];
  __bf16* lB0 = &Bs[(w * 16) * 32];

  f32x4 acc[4][2] = {};
  for (int k0 = 0; k0 < Kdim; k0 += 32) {
    __syncthreads();
    glds16(aS0 + k0, lA0);
    glds16(aS0 + K16 + k0, lA0 + 16 * 32);
    glds16(bS0 + k0, lB0);
    __syncthreads();
    bf16x8 af[4], bg[2];
#pragma unroll
    for (int rt = 0; rt < 4; rt++)
      af[rt] = *(const bf16x8*)&As[(wr * 64 + rt * 16 + l15) * 32 + quad * 8];
#pragma unroll
    for (int ct = 0; ct < 2; ct++)
      bg[ct] = *(const bf16x8*)&Bs[(wc * 32 + ct * 16 + l15) * 32 + quad * 8];
#pragma unroll
    for (int rt = 0; rt < 4; rt++)
#pragma unroll
      for (int ct = 0; ct < 2; ct++)
        acc[rt][ct] = mfma16(af[rt], bg[ct], acc[rt][ct]);
  }
#pragma unroll
  for (int rt = 0; rt < 4; rt++) {
    int row = m0 + wr * 64 + rt * 16 + quad * 4;
#pragma unroll
    for (int ct = 0; ct < 2; ct++) {
      int col = n0 + wc * 32 + ct * 16 + l15;
      float bcol = bias[col];
#pragma unroll
      for (int i = 0; i < 4; i++) {
        size_t idx = (size_t)(row + i) * Ndim + col;
        Cout[idx] = acc[rt][ct][i] + bcol + resid[idx];
      }
    }
  }
}

// ---------------- flash attention: swizzled LDS tiles, KV-split x2 ---------
// Block = (b,h,kvhalf,x): 128 Q-rows, 16 KV iters of 64 cols. K/Gk/V tiles
// staged once per block into XOR-swizzled stride-64 LDS (conflict-free b128
// reads, 40KB total -> 4 blocks/CU). No online max (logits bounded ~62);
// partial o,l (plain sums) written f32, merged by k_combine.
__global__ __launch_bounds__(256, 2) void k_flash(
    const __bf16* __restrict__ Q, const __bf16* __restrict__ K,
    const __bf16* __restrict__ Vt, const __bf16* __restrict__ Gq,
    const __bf16* __restrict__ Gk, const float* __restrict__ als,
    const float* __restrict__ psc, const float* __restrict__ nsc,
    float* __restrict__ Opart, float* __restrict__ lpart) {
  const int o = blockIdx.x;
  const int bh = o & 63, kv = (o >> 6) & 1, x = o >> 7;
  const int b = bh & 3, h = bh >> 2;
  const int t = threadIdx.x, w = t >> 6, lane = t & 63;
  const int quad = lane >> 4, l15 = lane & 15;
  const int row0 = x * 128 + w * 32;
  const float LOG2E = 1.44269504089f;
  const float sc2 = __expf(als[0]) * 0.125f * LOG2E;
  const float pos2 = psc[0] * LOG2E, neg2 = nsc[0] * LOG2E;

  __shared__ __align__(16) __bf16 Ks[64 * 64];
  __shared__ __align__(16) __bf16 Gs[64 * 64];
  __shared__ __align__(16) __bf16 Vs[64 * 64];
  __shared__ __align__(16) __bf16 plds[4][32 * 64];

  const __bf16* Qb = Q + ((size_t)(b * NN + row0)) * DB + h * DHD;
  const __bf16* Kb = K + ((size_t)b * NM) * DB + h * DHD;
  const __bf16* Vb = Vt + (size_t)(h * DHD) * (NB * NM) + (size_t)b * NM;
  const __bf16* Gqb = Gq + (size_t)(b * NN + row0) * DP;
  const __bf16* Gkb = Gk + (size_t)b * NM * DP;

  // staging: thread t covers rows r0, r0+32 at 16B chunk ch (swizzled dest)
  const int r0 = t >> 3, ch = t & 7, gc = ch * 8;
  const int sw0 = swz(r0, gc), sw1 = sw0 + 32 * 64;  // (r0+32)&7 == r0&7
  const int r1 = r0 + 32;

  bf16x8 qf[2][2], gqf[2][2];
#pragma unroll
  for (int rt = 0; rt < 2; rt++)
#pragma unroll
    for (int ks = 0; ks < 2; ks++) {
      qf[rt][ks] = *(const bf16x8*)(Qb + (size_t)(rt * 16 + l15) * DB + ks * 32 + quad * 8);
      gqf[rt][ks] = *(const bf16x8*)(Gqb + (size_t)(rt * 16 + l15) * DP + ks * 32 + quad * 8);
    }

  const int mlo = kv * 1024;
  // prefetch first slab
  bf16x8 kst0 = *(const bf16x8*)(Kb + (size_t)(mlo + r0) * DB + gc);
  bf16x8 kst1 = *(const bf16x8*)(Kb + (size_t)(mlo + r1) * DB + gc);
  bf16x8 gst0 = *(const bf16x8*)(Gkb + (size_t)(mlo + r0) * DP + gc);
  bf16x8 gst1 = *(const bf16x8*)(Gkb + (size_t)(mlo + r1) * DP + gc);
  bf16x8 vst0 = *(const bf16x8*)(Vb + (size_t)r0 * (NB * NM) + mlo + gc);
  bf16x8 vst1 = *(const bf16x8*)(Vb + (size_t)r1 * (NB * NM) + mlo + gc);

  float lrow[2][4] = {};
  f32x4 oacc[2][4] = {};
  f32x4 z4 = {0.f, 0.f, 0.f, 0.f};

  for (int m0 = mlo; m0 < mlo + 1024; m0 += 64) {
    __syncthreads();  // prior iter's tile reads complete
    *(bf16x8*)&Ks[sw0] = kst0;
    *(bf16x8*)&Ks[sw1] = kst1;
    *(bf16x8*)&Gs[sw0] = gst0;
    *(bf16x8*)&Gs[sw1] = gst1;
    *(bf16x8*)&Vs[sw0] = vst0;
    *(bf16x8*)&Vs[sw1] = vst1;
    __syncthreads();  // tiles visible
    if (m0 + 64 < mlo + 1024) {  // prefetch next slab during compute
      kst0 = *(const bf16x8*)(Kb + (size_t)(m0 + 64 + r0) * DB + gc);
      kst1 = *(const bf16x8*)(Kb + (size_t)(m0 + 64 + r1) * DB + gc);
      gst0 = *(const bf16x8*)(Gkb + (size_t)(m0 + 64 + r0) * DP + gc);
      gst1 = *(const bf16x8*)(Gkb + (size_t)(m0 + 64 + r1) * DP + gc);
      vst0 = *(const bf16x8*)(Vb + (size_t)r0 * (NB * NM) + m0 + 64 + gc);
      vst1 = *(const bf16x8*)(Vb + (size_t)r1 * (NB * NM) + m0 + 64 + gc);
    }
    bf16x8 kf[4][2], gkf[4][2];
#pragma unroll
    for (int ct = 0; ct < 4; ct++)
#pragma unroll
      for (int ks = 0; ks < 2; ks++) {
        int off = swz(ct * 16 + l15, ks * 32 + quad * 8);
        kf[ct][ks] = *(const bf16x8*)&Ks[off];
        gkf[ct][ks] = *(const bf16x8*)&Gs[off];
      }
#pragma unroll
    for (int rt = 0; rt < 2; rt++)
#pragma unroll
      for (int ct = 0; ct < 4; ct++) {
        f32x4 s = mfma16(qf[rt][1], kf[ct][1], mfma16(qf[rt][0], kf[ct][0], z4));
        f32x4 bg = mfma16(gqf[rt][1], gkf[ct][1], mfma16(gqf[rt][0], gkf[ct][0], z4));
#pragma unroll
        for (int i = 0; i < 4; i++) {
          float bb = bg[i];
          float scl = bb > 0.f ? pos2 : neg2;
          float p = __builtin_amdgcn_exp2f(fmaf(bb, scl, s[i] * sc2));
          lrow[rt][i] += p;
          plds[w][swz(rt * 16 + quad * 4 + i, ct * 16 + l15)] = (__bf16)p;
        }
      }
    // P (C-layout) -> per-wave swizzled LDS -> A-frags; V from shared tile
    bf16x8 pf[2][2], vf[4][2];
#pragma unroll
    for (int rt = 0; rt < 2; rt++)
#pragma unroll
      for (int ms = 0; ms < 2; ms++)
        pf[rt][ms] = *(const bf16x8*)&plds[w][swz(rt * 16 + l15, ms * 32 + quad * 8)];
#pragma unroll
    for (int dt = 0; dt < 4; dt++)
#pragma unroll
      for (int ms = 0; ms < 2; ms++)
        vf[dt][ms] = *(const bf16x8*)&Vs[swz(dt * 16 + l15, ms * 32 + quad * 8)];
#pragma unroll
    for (int rt = 0; rt < 2; rt++)
#pragma unroll
      for (int dt = 0; dt < 4; dt++) {
        oacc[rt][dt] = mfma16(pf[rt][0], vf[dt][0], oacc[rt][dt]);
        oacc[rt][dt] = mfma16(pf[rt][1], vf[dt][1], oacc[rt][dt]);
      }
  }
  // l reduction over 16 column-lanes, then store f32 partials
  float* op = Opart + ((size_t)kv * NB * NN + b * NN + row0) * DB + h * 64;
  float* lp = lpart + ((size_t)kv * NB * NN + b * NN + row0) * DH + h;
#pragma unroll
  for (int rt = 0; rt < 2; rt++)
#pragma unroll
    for (int i = 0; i < 4; i++) {
      float l = lrow[rt][i];
#pragma unroll
      for (int o2 = 1; o2 < 16; o2 <<= 1) l += __shfl_xor(l, o2, 64);
      int r = rt * 16 + quad * 4 + i;
#pragma unroll
      for (int dt = 0; dt < 4; dt++)
        op[(size_t)r * DB + dt * 16 + l15] = oacc[rt][dt][i];
      if (l15 == 0) lp[(size_t)r * DH] = l;
    }
}

// ---------------- combine KV halves: attn = (O0+O1)/(l0+l1) -> bf16 --------
__global__ __launch_bounds__(256) void k_combine(
    const float* __restrict__ Opart, const float* __restrict__ lpart,
    __bf16* __restrict__ attn) {
  const int bn = blockIdx.x;  // b*NN + n
  const int t = threadIdx.x, c = t * 4, h = c >> 6;
  const float4 o0 = *(const float4*)&Opart[(size_t)bn * DB + c];
  const float4 o1 = *(const float4*)&Opart[((size_t)NB * NN + bn) * DB + c];
  float l0 = lpart[(size_t)bn * DH + h];
  float l1 = lpart[((size_t)NB * NN + bn) * DH + h];
  float inv = 1.f / (l0 + l1);
  __bf16* dst = attn + (size_t)bn * DB + c;
  dst[0] = (__bf16)((o0.x + o1.x) * inv);
  dst[1] = (__bf16)((o0.y + o1.y) * inv);
  dst[2] = (__bf16)((o0.z + o1.z) * inv);
  dst[3] = (__bf16)((o0.w + o1.w) * inv);
}

// ---------------------------------------------------------------------------
extern "C" void kernel_launch(void* const* d_in, const int* in_sizes, int n_in,
                              void* d_out, int out_size, void* d_ws, size_t ws_size,
                              hipStream_t stream) {
  const float* dataset = (const float*)d_in[0];
  const float* visual = (const float*)d_in[1];
  const float* wq_w = (const float*)d_in[2];
  const float* wq_b = (const float*)d_in[3];
  const float* wk_w = (const float*)d_in[4];
  const float* wk_b = (const float*)d_in[5];
  const float* wv_w = (const float*)d_in[6];
  const float* wv_b = (const float*)d_in[7];
  const float* wo_w = (const float*)d_in[8];
  const float* wo_b = (const float*)d_in[9];
  const float* gq_w = (const float*)d_in[10];
  const float* gq_b = (const float*)d_in[11];
  const float* gk_w = (const float*)d_in[12];
  const float* gk_b = (const float*)d_in[13];
  const float* pos_scale = (const float*)d_in[14];
  const float* neg_scale = (const float*)d_in[15];
  const float* als = (const float*)d_in[16];
  const float* ln_q_g = (const float*)d_in[17];
  const float* ln_q_b = (const float*)d_in[18];
  const float* ln_kv_g = (const float*)d_in[19];
  const float* ln_kv_b = (const float*)d_in[20];
  const float* ln_out_g = (const float*)d_in[21];
  const float* ln_out_b = (const float*)d_in[22];
  const float* ff1_w = (const float*)d_in[23];
  const float* ff1_b = (const float*)d_in[24];
  const float* ff2_w = (const float*)d_in[25];
  const float* ff2_b = (const float*)d_in[26];

  char* ws = (char*)d_ws;
  size_t off = 0;
  auto alloc = [&](size_t bytes) {
    size_t o = off;
    off += (bytes + 255) & ~(size_t)255;
    return o;
  };
  __bf16* t_wq = (__bf16*)(ws + alloc((size_t)1024 * 1024 * 2));
  __bf16* t_wk = (__bf16*)(ws + alloc((size_t)1024 * 1024 * 2));
  __bf16* t_wv = (__bf16*)(ws + alloc((size_t)1024 * 1024 * 2));
  __bf16* t_wo = (__bf16*)(ws + alloc((size_t)1024 * 1024 * 2));
  __bf16* t_ff1 = (__bf16*)(ws + alloc((size_t)2048 * 1024 * 2));
  __bf16* t_ff2 = (__bf16*)(ws + alloc((size_t)1024 * 2048 * 2));
  __bf16* t_gq = (__bf16*)(ws + alloc((size_t)64 * 1024 * 2));
  __bf16* t_gk = (__bf16*)(ws + alloc((size_t)64 * 1024 * 2));
  size_t qin_off = alloc((size_t)4096 * 1024 * 2);   // aliased as hbuf later
  size_t kvin_off = alloc((size_t)8192 * 1024 * 2);  // aliased as out1(f32) later
  __bf16* qin = (__bf16*)(ws + qin_off);
  __bf16* kvin = (__bf16*)(ws + kvin_off);
  __bf16* geoq = (__bf16*)(ws + alloc((size_t)4096 * 64 * 2));
  __bf16* geok = (__bf16*)(ws + alloc((size_t)8192 * 64 * 2));
  float* sums = (float*)(ws + alloc((size_t)2 * 4 * 64 * 4));
  __bf16* qb = (__bf16*)(ws + alloc((size_t)4096 * 1024 * 2));
  __bf16* kb = (__bf16*)(ws + alloc((size_t)8192 * 1024 * 2));
  __bf16* vtb = (__bf16*)(ws + alloc((size_t)1024 * 8192 * 2));  // V^T [ch][tok]
  __bf16* attn = (__bf16*)(ws + alloc((size_t)4096 * 1024 * 2));
  __bf16* ffh = (__bf16*)(ws + alloc((size_t)4096 * 2048 * 2));
  float* opart = (float*)(ws + alloc((size_t)2 * 4096 * 1024 * 4));  // 32MB
  float* lpart = (float*)(ws + alloc((size_t)2 * 4096 * 16 * 4));
  // aliases (lifetimes disjoint):
  float* out1 = (float*)(ws + kvin_off);   // f32 [4096,1024] over kv_in
  __bf16* hbuf = (__bf16*)(ws + qin_off);  // bf16 [4096,1024] over q_in
  float* outp = (float*)d_out;

  dim3 blk(256);
  // 1. all weight transposes in one launch
  k_transpose_all<<<8320, blk, 0, stream>>>(wq_w, wk_w, wv_w, wo_w, ff1_w, ff2_w,
                                            gq_w, gk_w, t_wq, t_wk, t_wv, t_wo,
                                            t_ff1, t_ff2, t_gq, t_gk);
  // 2. both input layernorms in one launch
  k_layernorm2<<<12288, blk, 0, stream>>>(dataset, ln_q_g, ln_q_b, qin,
                                          visual, ln_kv_g, ln_kv_b, kvin);
  // 3. geo path
  k_geo<<<384, blk, 0, stream>>>(qin, kvin, t_gq, t_gk, gq_b, gk_b, geoq, geok);
  hipMemsetAsync(sums, 0, 2 * 4 * 64 * 4, stream);
  k_l2sum<<<dim3(16, 4, 2), blk, 0, stream>>>(geoq, geok, sums);
  k_l2scale<<<dim3(16, 4), blk, 0, stream>>>(geok, sums);
  // 4. fused QKV projections
  k_qkv<<<1280, blk, 0, stream>>>(qin, kvin, t_wq, t_wk, t_wv,
                                  wq_b, wk_b, wv_b, qb, kb, vtb);
  // 5. flash attention (KV-split x2) + combine
  k_flash<<<1024, blk, 0, stream>>>(qb, kb, vtb, geoq, geok, als,
                                    pos_scale, neg_scale, opart, lpart);
  k_combine<<<4096, blk, 0, stream>>>(opart, lpart, attn);
  // 6. output projection + residual, LN, FFN
  k_gemmn64<<<dim3(16, 32), blk, 0, stream>>>(attn, t_wo, wo_b, dataset, out1,
                                              1024, 1024);
  k_layernorm<<<4096, blk, 0, stream>>>(out1, ln_out_g, ln_out_b, hbuf);
  k_gemm128g<<<dim3(16, 32), blk, 0, stream>>>(hbuf, t_ff1, ff1_b, ffh,
                                               2048, 1024);
  k_gemmn64<<<dim3(16, 32), blk, 0, stream>>>(ffh, t_ff2, ff2_b, out1, outp,
                                              1024, 2048);
}

// Round 7
// 435.078 us; speedup vs baseline: 1.0548x; 1.0548x over previous
//
#include <hip/hip_runtime.h>

// ---------------------------------------------------------------------------
// BiasCrossAttentionFusion on gfx950 — round 6.
//   R6 vs R5 (459us, flash 91.7us): R5 proved flash is issue-bound in the
//   softmax block (conflicts 0 yet dur flat; KV-split neutral: occupancy flat,
//   FETCH doubled). Fix: compute S^T = K*Q^T (swap MFMA operands) so the
//   C-layout gives 4 consecutive-m values per lane -> P scatter becomes
//   8x ds_write_b64 (pk-cvt) instead of 32x ds_write_u16; lrow becomes lane
//   partials (+2 end shuffles). Revert KV-split (grid 512, direct bf16 out,
//   combine kernel deleted). K/G/V tiles + PV/O layouts unchanged.
// ---------------------------------------------------------------------------

typedef __bf16 bf16x8 __attribute__((ext_vector_type(8)));
typedef __bf16 bf16x4 __attribute__((ext_vector_type(4)));
typedef float  f32x4  __attribute__((ext_vector_type(4)));

__device__ inline f32x4 mfma16(bf16x8 a, bf16x8 b, f32x4 c) {
  return __builtin_amdgcn_mfma_f32_16x16x32_bf16(a, b, c, 0, 0, 0);
}

__device__ inline void glds16(const void* g, void* l) {
  __builtin_amdgcn_global_load_lds(
      (const __attribute__((address_space(1))) void*)g,
      (__attribute__((address_space(3))) void*)l, 16, 0, 0);
}

// swizzled LDS offset for a 64-elem bf16 row: 16B-chunk index XOR (row&7)
__device__ inline int swz(int row, int col) {
  return row * 64 + ((((col >> 3) ^ (row & 7)) << 3) | (col & 7));
}

#define DB 1024
#define DH 16
#define DHD 64
#define DP 64
#define NB 4
#define NN 1024
#define NM 2048

// ---------------- all weight transposes (f32 [K,O] -> bf16 [O,K]) ----------
__global__ __launch_bounds__(256) void k_transpose_all(
    const float* __restrict__ w0, const float* __restrict__ w1,
    const float* __restrict__ w2, const float* __restrict__ w3,
    const float* __restrict__ f1, const float* __restrict__ f2,
    const float* __restrict__ g0, const float* __restrict__ g1,
    __bf16* __restrict__ o0, __bf16* __restrict__ o1,
    __bf16* __restrict__ o2, __bf16* __restrict__ o3,
    __bf16* __restrict__ of1, __bf16* __restrict__ of2,
    __bf16* __restrict__ og0, __bf16* __restrict__ og1) {
  __shared__ float tile[32][33];
  int id = blockIdx.x;
  const float* in;
  __bf16* out;
  int K, O, x, y;
  if (id < 4096) {
    int mi = id >> 10, r = id & 1023;
    in = mi == 0 ? w0 : mi == 1 ? w1 : mi == 2 ? w2 : w3;
    out = mi == 0 ? o0 : mi == 1 ? o1 : mi == 2 ? o2 : o3;
    K = 1024; O = 1024; x = r & 31; y = r >> 5;
  } else if (id < 6144) {
    int r = id - 4096; in = f1; out = of1; K = 1024; O = 2048; x = r & 63; y = r >> 6;
  } else if (id < 8192) {
    int r = id - 6144; in = f2; out = of2; K = 2048; O = 1024; x = r & 31; y = r >> 5;
  } else if (id < 8256) {
    int r = id - 8192; in = g0; out = og0; K = 1024; O = 64; x = r & 1; y = r >> 1;
  } else {
    int r = id - 8256; in = g1; out = og1; K = 1024; O = 64; x = r & 1; y = r >> 1;
  }
  int k0 = y * 32, o0c = x * 32;
  int tx = threadIdx.x & 31, ty = threadIdx.x >> 5;
#pragma unroll
  for (int r = ty; r < 32; r += 8)
    tile[r][tx] = in[(size_t)(k0 + r) * O + (o0c + tx)];
  __syncthreads();
#pragma unroll
  for (int r = ty; r < 32; r += 8)
    out[(size_t)(o0c + r) * K + (k0 + tx)] = (__bf16)tile[tx][r];
}

// ---------------- LayerNorm D=1024, one block/row, bf16 out ----------------
__device__ inline void ln_body(const float* __restrict__ x,
                               const float* __restrict__ g,
                               const float* __restrict__ bb,
                               __bf16* __restrict__ y, size_t row) {
  int t = threadIdx.x;
  float4 v = ((const float4*)(x + row * 1024))[t];
  float s = v.x + v.y + v.z + v.w;
  float ss = v.x * v.x + v.y * v.y + v.z * v.z + v.w * v.w;
#pragma unroll
  for (int o = 32; o; o >>= 1) {
    s += __shfl_down(s, o, 64);
    ss += __shfl_down(ss, o, 64);
  }
  __shared__ float r1[4], r2[4];
  if ((t & 63) == 0) { r1[t >> 6] = s; r2[t >> 6] = ss; }
  __syncthreads();
  s = r1[0] + r1[1] + r1[2] + r1[3];
  ss = r2[0] + r2[1] + r2[2] + r2[3];
  float mu = s * (1.f / 1024.f);
  float rstd = rsqrtf(ss * (1.f / 1024.f) - mu * mu + 1e-5f);
  float4 gv = ((const float4*)g)[t];
  float4 bv = ((const float4*)bb)[t];
  __bf16* yr = y + row * 1024 + t * 4;
  yr[0] = (__bf16)((v.x - mu) * rstd * gv.x + bv.x);
  yr[1] = (__bf16)((v.y - mu) * rstd * gv.y + bv.y);
  yr[2] = (__bf16)((v.z - mu) * rstd * gv.z + bv.z);
  yr[3] = (__bf16)((v.w - mu) * rstd * gv.w + bv.w);
}

__global__ __launch_bounds__(256) void k_layernorm(
    const float* __restrict__ x, const float* __restrict__ g,
    const float* __restrict__ bb, __bf16* __restrict__ y) {
  ln_body(x, g, bb, y, blockIdx.x);
}

__global__ __launch_bounds__(256) void k_layernorm2(
    const float* __restrict__ x1, const float* __restrict__ g1,
    const float* __restrict__ b1, __bf16* __restrict__ y1,
    const float* __restrict__ x2, const float* __restrict__ g2,
    const float* __restrict__ b2, __bf16* __restrict__ y2) {
  int row = blockIdx.x;
  if (row < 4096) ln_body(x1, g1, b1, y1, row);
  else ln_body(x2, g2, b2, y2, row - 4096);
}

// ---------------- geo projections: q(128 blk) + kv(256 blk), 32x64 tiles ---
__global__ __launch_bounds__(256) void k_geo(
    const __bf16* __restrict__ qin, const __bf16* __restrict__ kvin,
    const __bf16* __restrict__ gqw, const __bf16* __restrict__ gkw,
    const float* __restrict__ gqb, const float* __restrict__ gkb,
    __bf16* __restrict__ geoq, __bf16* __restrict__ geok) {
  const int blk = blockIdx.x;
  const bool isq = blk < 128;
  const __bf16* A = isq ? qin : kvin;
  const __bf16* Bt = isq ? gqw : gkw;
  const float* bias = isq ? gqb : gkb;
  __bf16* C = isq ? geoq : geok;
  const int row0 = (isq ? blk : blk - 128) * 32;
  __shared__ __align__(16) __bf16 As[32][72], Bs[64][72];
  const int t = threadIdx.x, lane = t & 63, w = t >> 6;
  const int quad = lane >> 4, l15 = lane & 15;
  const int wr = w >> 1, wc = w & 1;
  const int sr = t >> 3, skc = (t & 7) * 8;
  const __bf16* aP = A + (size_t)(row0 + sr) * 1024 + skc;
  const __bf16* bP0 = Bt + (size_t)sr * 1024 + skc;
  const __bf16* bP1 = Bt + (size_t)(sr + 32) * 1024 + skc;
  bf16x8 av = *(const bf16x8*)aP;
  bf16x8 bv0 = *(const bf16x8*)bP0;
  bf16x8 bv1 = *(const bf16x8*)bP1;
  f32x4 acc[2] = {};
  for (int k0 = 0; k0 < 1024; k0 += 64) {
    __syncthreads();
    *(bf16x8*)&As[sr][skc] = av;
    *(bf16x8*)&Bs[sr][skc] = bv0;
    *(bf16x8*)&Bs[sr + 32][skc] = bv1;
    __syncthreads();
    if (k0 + 64 < 1024) {
      av = *(const bf16x8*)(aP + k0 + 64);
      bv0 = *(const bf16x8*)(bP0 + k0 + 64);
      bv1 = *(const bf16x8*)(bP1 + k0 + 64);
    }
#pragma unroll
    for (int ks = 0; ks < 2; ks++) {
      bf16x8 af = *(const bf16x8*)&As[wr * 16 + l15][ks * 32 + quad * 8];
#pragma unroll
      for (int ct = 0; ct < 2; ct++) {
        bf16x8 bfr = *(const bf16x8*)&Bs[wc * 32 + ct * 16 + l15][ks * 32 + quad * 8];
        acc[ct] = mfma16(af, bfr, acc[ct]);
      }
    }
  }
#pragma unroll
  for (int ct = 0; ct < 2; ct++) {
    int col = wc * 32 + ct * 16 + l15;
    float bc = bias[col];
#pragma unroll
    for (int i = 0; i < 4; i++) {
      int row = row0 + wr * 16 + quad * 4 + i;
      C[(size_t)row * 64 + col] = (__bf16)(acc[ct][i] + bc);
    }
  }
}

// ---------------- l2 norms, phase 1: column sum-of-squares -----------------
__global__ __launch_bounds__(256) void k_l2sum(
    const __bf16* __restrict__ gq, const __bf16* __restrict__ gk,
    float* __restrict__ sums) {
  int chunk = blockIdx.x, b = blockIdx.y, z = blockIdx.z;
  if (z == 0 && chunk >= 8) return;
  const __bf16* src = z ? gk : gq;
  int rows = z ? 2048 : 1024;
  const unsigned* base = (const unsigned*)(src + (size_t)b * rows * 64) + chunk * 128 * 32;
  int t = threadIdx.x, c = t & 31, ro = t >> 5;
  float s0 = 0.f, s1 = 0.f;
  for (int r = ro; r < 128; r += 8) {
    unsigned u = base[r * 32 + c];
    float f0 = __uint_as_float(u << 16);
    float f1 = __uint_as_float(u & 0xffff0000u);
    s0 += f0 * f0;
    s1 += f1 * f1;
  }
  __shared__ float ls[64];
  if (t < 64) ls[t] = 0.f;
  __syncthreads();
  atomicAdd(&ls[c * 2], s0);
  atomicAdd(&ls[c * 2 + 1], s1);
  __syncthreads();
  if (t < 64) atomicAdd(&sums[z * 256 + b * 64 + t], ls[t]);
}

// ---------------- l2 phase 2: scale geo_k by 1/(||q_p||*||k_p||) -----------
__global__ __launch_bounds__(256) void k_l2scale(
    __bf16* __restrict__ gk, const float* __restrict__ sums) {
  int chunk = blockIdx.x, b = blockIdx.y;
  unsigned* base = (unsigned*)(gk + (size_t)b * 2048 * 64) + chunk * 128 * 32;
  int t = threadIdx.x, c = t & 31, ro = t >> 5;
  float sq0 = sums[b * 64 + c * 2], sq1 = sums[b * 64 + c * 2 + 1];
  float sk0 = sums[256 + b * 64 + c * 2], sk1 = sums[256 + b * 64 + c * 2 + 1];
  float m0 = 1.f / (fmaxf(sqrtf(sq0), 1e-12f) * fmaxf(sqrtf(sk0), 1e-12f));
  float m1 = 1.f / (fmaxf(sqrtf(sq1), 1e-12f) * fmaxf(sqrtf(sk1), 1e-12f));
  for (int r = ro; r < 128; r += 8) {
    unsigned u = base[r * 32 + c];
    float f0 = __uint_as_float(u << 16) * m0;
    float f1 = __uint_as_float(u & 0xffff0000u) * m1;
    unsigned short h0 = __builtin_bit_cast(unsigned short, (__bf16)f0);
    unsigned short h1 = __builtin_bit_cast(unsigned short, (__bf16)f1);
    base[r * 32 + c] = (unsigned)h0 | ((unsigned)h1 << 16);
  }
}

// ---------------- fused QKV: qb(256) + kb(512) + vtb(512) blocks -----------
__global__ __launch_bounds__(256, 3) void k_qkv(
    const __bf16* __restrict__ qin, const __bf16* __restrict__ kvin,
    const __bf16* __restrict__ twq, const __bf16* __restrict__ twk,
    const __bf16* __restrict__ twv, const float* __restrict__ qbias,
    const float* __restrict__ kbias, const float* __restrict__ vbias,
    __bf16* __restrict__ qb, __bf16* __restrict__ kb, __bf16* __restrict__ vtb) {
  int id = blockIdx.x;
  const __bf16 *A, *Bt;
  const float* bias;
  __bf16* C;
  int my, nx, Ndim;
  bool rowbias;
  if (id < 256) {
    A = qin; Bt = twq; bias = qbias; C = qb;
    nx = id & 7; my = id >> 3; Ndim = 1024; rowbias = false;
  } else if (id < 768) {
    id -= 256;
    A = kvin; Bt = twk; bias = kbias; C = kb;
    nx = id & 7; my = id >> 3; Ndim = 1024; rowbias = false;
  } else {
    id -= 768;
    A = twv; Bt = kvin; bias = vbias; C = vtb;
    nx = id & 63; my = id >> 6; Ndim = 8192; rowbias = true;
  }
  const int Kdim = 1024;
  __shared__ __align__(16) __bf16 As[128 * 32];
  __shared__ __align__(16) __bf16 Bs[128 * 32];
  const int m0 = my * 128, n0 = nx * 128;
  const int t = threadIdx.x, lane = t & 63, w = t >> 6;
  const int quad = lane >> 4, l15 = lane & 15;
  const int wr = w >> 1, wc = w & 1;
  const int srow = lane >> 2, scol = (lane & 3) * 8;
  const __bf16* aS0 = A + (size_t)(m0 + w * 32 + srow) * Kdim + scol;
  const __bf16* bS0 = Bt + (size_t)(n0 + w * 32 + srow) * Kdim + scol;
  const size_t K16 = (size_t)16 * Kdim;
  __bf16* lA0 = &As[(w * 32) * 32];
  __bf16* lB0 = &Bs[(w * 32) * 32];

  f32x4 acc[4][4] = {};
  for (int k0 = 0; k0 < Kdim; k0 += 32) {
    __syncthreads();
    glds16(aS0 + k0, lA0);
    glds16(aS0 + K16 + k0, lA0 + 16 * 32);
    glds16(bS0 + k0, lB0);
    glds16(bS0 + K16 + k0, lB0 + 16 * 32);
    __syncthreads();
    bf16x8 af[4], bg[4];
#pragma unroll
    for (int rt = 0; rt < 4; rt++)
      af[rt] = *(const bf16x8*)&As[(wr * 64 + rt * 16 + l15) * 32 + quad * 8];
#pragma unroll
    for (int ct = 0; ct < 4; ct++)
      bg[ct] = *(const bf16x8*)&Bs[(wc * 64 + ct * 16 + l15) * 32 + quad * 8];
#pragma unroll
    for (int rt = 0; rt < 4; rt++)
#pragma unroll
      for (int ct = 0; ct < 4; ct++)
        acc[rt][ct] = mfma16(af[rt], bg[ct], acc[rt][ct]);
  }
#pragma unroll
  for (int rt = 0; rt < 4; rt++) {
    int row = m0 + wr * 64 + rt * 16 + quad * 4;
#pragma unroll
    for (int ct = 0; ct < 4; ct++) {
      int col = n0 + wc * 64 + ct * 16 + l15;
      float bcol = rowbias ? 0.f : bias[col];
#pragma unroll
      for (int i = 0; i < 4; i++) {
        float vv = acc[rt][ct][i] + (rowbias ? bias[row + i] : bcol);
        C[(size_t)(row + i) * Ndim + col] = (__bf16)vv;
      }
    }
  }
}

// ---------------- big GEMM 128x128 (ff1: gelu epilogue) --------------------
__global__ __launch_bounds__(256, 3) void k_gemm128g(
    const __bf16* __restrict__ A, const __bf16* __restrict__ Bt,
    const float* __restrict__ bias, __bf16* __restrict__ Cout,
    int Ndim, int Kdim) {
  __shared__ __align__(16) __bf16 As[128 * 32];
  __shared__ __align__(16) __bf16 Bs[128 * 32];
  const int m0 = blockIdx.y * 128, n0 = blockIdx.x * 128;
  const int t = threadIdx.x, lane = t & 63, w = t >> 6;
  const int quad = lane >> 4, l15 = lane & 15;
  const int wr = w >> 1, wc = w & 1;
  const int srow = lane >> 2, scol = (lane & 3) * 8;
  const __bf16* aS0 = A + (size_t)(m0 + w * 32 + srow) * Kdim + scol;
  const __bf16* bS0 = Bt + (size_t)(n0 + w * 32 + srow) * Kdim + scol;
  const size_t K16 = (size_t)16 * Kdim;
  __bf16* lA0 = &As[(w * 32) * 32];
  __bf16* lB0 = &Bs[(w * 32) * 32];

  f32x4 acc[4][4] = {};
  for (int k0 = 0; k0 < Kdim; k0 += 32) {
    __syncthreads();
    glds16(aS0 + k0, lA0);
    glds16(aS0 + K16 + k0, lA0 + 16 * 32);
    glds16(bS0 + k0, lB0);
    glds16(bS0 + K16 + k0, lB0 + 16 * 32);
    __syncthreads();
    bf16x8 af[4], bg[4];
#pragma unroll
    for (int rt = 0; rt < 4; rt++)
      af[rt] = *(const bf16x8*)&As[(wr * 64 + rt * 16 + l15) * 32 + quad * 8];
#pragma unroll
    for (int ct = 0; ct < 4; ct++)
      bg[ct] = *(const bf16x8*)&Bs[(wc * 64 + ct * 16 + l15) * 32 + quad * 8];
#pragma unroll
    for (int rt = 0; rt < 4; rt++)
#pragma unroll
      for (int ct = 0; ct < 4; ct++)
        acc[rt][ct] = mfma16(af[rt], bg[ct], acc[rt][ct]);
  }
#pragma unroll
  for (int rt = 0; rt < 4; rt++) {
    int row = m0 + wr * 64 + rt * 16 + quad * 4;
#pragma unroll
    for (int ct = 0; ct < 4; ct++) {
      int col = n0 + wc * 64 + ct * 16 + l15;
      float bcol = bias[col];
#pragma unroll
      for (int i = 0; i < 4; i++) {
        float vv = acc[rt][ct][i] + bcol;
        Cout[(size_t)(row + i) * Ndim + col] =
            (__bf16)(0.5f * vv * (1.f + erff(vv * 0.70710678118f)));
      }
    }
  }
}

// ---------------- GEMM 128x64 tile (wo / ff2): +bias +resid -> f32 ---------
__global__ __launch_bounds__(256, 2) void k_gemmn64(
    const __bf16* __restrict__ A, const __bf16* __restrict__ Bt,
    const float* __restrict__ bias, const float* __restrict__ resid,
    float* __restrict__ Cout, int Ndim, int Kdim) {
  __shared__ __align__(16) __bf16 As[128 * 32];
  __shared__ __align__(16) __bf16 Bs[64 * 32];
  const int m0 = blockIdx.y * 128, n0 = blockIdx.x * 64;
  const int t = threadIdx.x, lane = t & 63, w = t >> 6;
  const int quad = lane >> 4, l15 = lane & 15;
  const int wr = w >> 1, wc = w & 1;
  const int srow = lane >> 2, scol = (lane & 3) * 8;
  const __bf16* aS0 = A + (size_t)(m0 + w * 32 + srow) * Kdim + scol;
  const __bf16* bS0 = Bt + (size_t)(n0 + w * 16 + srow) * Kdim + scol;
  const size_t K16 = (size_t)16 * Kdim;
  __bf16* lA0 = &As[(w * 32) * 32];
  __bf16* lB0 = &Bs[(w * 16) * 32];

  f32x4 acc[4][2] = {};
  for (int k0 = 0; k0 < Kdim; k0 += 32) {
    __syncthreads();
    glds16(aS0 + k0, lA0);
    glds16(aS0 + K16 + k0, lA0 + 16 * 32);
    glds16(bS0 + k0, lB0);
    __syncthreads();
    bf16x8 af[4], bg[2];
#pragma unroll
    for (int rt = 0; rt < 4; rt++)
      af[rt] = *(const bf16x8*)&As[(wr * 64 + rt * 16 + l15) * 32 + quad * 8];
#pragma unroll
    for (int ct = 0; ct < 2; ct++)
      bg[ct] = *(const bf16x8*)&Bs[(wc * 32 + ct * 16 + l15) * 32 + quad * 8];
#pragma unroll
    for (int rt = 0; rt < 4; rt++)
#pragma unroll
      for (int ct = 0; ct < 2; ct++)
        acc[rt][ct] = mfma16(af[rt], bg[ct], acc[rt][ct]);
  }
#pragma unroll
  for (int rt = 0; rt < 4; rt++) {
    int row = m0 + wr * 64 + rt * 16 + quad * 4;
#pragma unroll
    for (int ct = 0; ct < 2; ct++) {
      int col = n0 + wc * 32 + ct * 16 + l15;
      float bcol = bias[col];
#pragma unroll
      for (int i = 0; i < 4; i++) {
        size_t idx = (size_t)(row + i) * Ndim + col;
        Cout[idx] = acc[rt][ct][i] + bcol + resid[idx];
      }
    }
  }
}

// ---------------- flash attention: S^T form, vectorized P scatter ----------
// Block = (b,h,x): 128 Q rows, 32 KV iters of 64 cols. K/Gk/V 64x64 tiles
// staged once per block (swizzled, conflict-free). S^T = K*Q^T so C-layout
// gives 4 consecutive m per lane: P written as 8x ds_write_b64 (pk-cvt) into
// swizzled per-wave tile, read back as b128 A-frags for PV. No online max
// (logits bounded ~62). lrow = per-lane partials, reduced at end (xor 16/32).
__global__ __launch_bounds__(256, 2) void k_flash(
    const __bf16* __restrict__ Q, const __bf16* __restrict__ K,
    const __bf16* __restrict__ Vt, const __bf16* __restrict__ Gq,
    const __bf16* __restrict__ Gk, const float* __restrict__ als,
    const float* __restrict__ psc, const float* __restrict__ nsc,
    __bf16* __restrict__ Out) {
  const int o = blockIdx.x;
  const int bh = o & 63, x = o >> 6;
  const int b = bh & 3, h = bh >> 2;
  const int t = threadIdx.x, w = t >> 6, lane = t & 63;
  const int quad = lane >> 4, l15 = lane & 15;
  const int row0 = x * 128 + w * 32;
  const float LOG2E = 1.44269504089f;
  const float sc2 = __expf(als[0]) * 0.125f * LOG2E;
  const float pos2 = psc[0] * LOG2E, neg2 = nsc[0] * LOG2E;

  __shared__ __align__(16) __bf16 Ks[64 * 64];
  __shared__ __align__(16) __bf16 Gs[64 * 64];
  __shared__ __align__(16) __bf16 Vs[64 * 64];
  __shared__ __align__(16) __bf16 Ps[4][32 * 64];

  const __bf16* Qb = Q + ((size_t)(b * NN + row0)) * DB + h * DHD;
  const __bf16* Kb = K + ((size_t)b * NM) * DB + h * DHD;
  const __bf16* Vb = Vt + (size_t)(h * DHD) * (NB * NM) + (size_t)b * NM;
  const __bf16* Gqb = Gq + (size_t)(b * NN + row0) * DP;
  const __bf16* Gkb = Gk + (size_t)b * NM * DP;

  // staging: thread t covers rows r0, r0+32 at 16B chunk (swizzled dest)
  const int r0 = t >> 3, gc = (t & 7) * 8;
  const int sw0 = swz(r0, gc), sw1 = sw0 + 32 * 64;  // (r0+32)&7 == r0&7
  const int r1 = r0 + 32;

  bf16x8 qf[2][2], gqf[2][2];
#pragma unroll
  for (int rt = 0; rt < 2; rt++)
#pragma unroll
    for (int ks = 0; ks < 2; ks++) {
      qf[rt][ks] = *(const bf16x8*)(Qb + (size_t)(rt * 16 + l15) * DB + ks * 32 + quad * 8);
      gqf[rt][ks] = *(const bf16x8*)(Gqb + (size_t)(rt * 16 + l15) * DP + ks * 32 + quad * 8);
    }

  // prefetch first slab
  bf16x8 kst0 = *(const bf16x8*)(Kb + (size_t)r0 * DB + gc);
  bf16x8 kst1 = *(const bf16x8*)(Kb + (size_t)r1 * DB + gc);
  bf16x8 gst0 = *(const bf16x8*)(Gkb + (size_t)r0 * DP + gc);
  bf16x8 gst1 = *(const bf16x8*)(Gkb + (size_t)r1 * DP + gc);
  bf16x8 vst0 = *(const bf16x8*)(Vb + (size_t)r0 * (NB * NM) + gc);
  bf16x8 vst1 = *(const bf16x8*)(Vb + (size_t)r1 * (NB * NM) + gc);

  float lrowq[2] = {};
  f32x4 oacc[2][4] = {};
  f32x4 z4 = {0.f, 0.f, 0.f, 0.f};

  for (int m0 = 0; m0 < NM; m0 += 64) {
    __syncthreads();  // prior iter's tile reads complete
    *(bf16x8*)&Ks[sw0] = kst0;
    *(bf16x8*)&Ks[sw1] = kst1;
    *(bf16x8*)&Gs[sw0] = gst0;
    *(bf16x8*)&Gs[sw1] = gst1;
    *(bf16x8*)&Vs[sw0] = vst0;
    *(bf16x8*)&Vs[sw1] = vst1;
    __syncthreads();  // tiles visible
    if (m0 + 64 < NM) {  // prefetch next slab during compute
      kst0 = *(const bf16x8*)(Kb + (size_t)(m0 + 64 + r0) * DB + gc);
      kst1 = *(const bf16x8*)(Kb + (size_t)(m0 + 64 + r1) * DB + gc);
      gst0 = *(const bf16x8*)(Gkb + (size_t)(m0 + 64 + r0) * DP + gc);
      gst1 = *(const bf16x8*)(Gkb + (size_t)(m0 + 64 + r1) * DP + gc);
      vst0 = *(const bf16x8*)(Vb + (size_t)r0 * (NB * NM) + m0 + 64 + gc);
      vst1 = *(const bf16x8*)(Vb + (size_t)r1 * (NB * NM) + m0 + 64 + gc);
    }
    bf16x8 kf[4][2], gkf[4][2];
#pragma unroll
    for (int ct = 0; ct < 4; ct++)
#pragma unroll
      for (int ks = 0; ks < 2; ks++) {
        int off = swz(ct * 16 + l15, ks * 32 + quad * 8);
        kf[ct][ks] = *(const bf16x8*)&Ks[off];
        gkf[ct][ks] = *(const bf16x8*)&Gs[off];
      }
    // S^T tiles: D[m-block ct][n-block rt], A=K rows (m), B=Q rows (n).
    // C-layout: col = n = l15, row = m = quad*4+i -> 4 consecutive m/lane.
#pragma unroll
    for (int ct = 0; ct < 4; ct++)
#pragma unroll
      for (int rt = 0; rt < 2; rt++) {
        f32x4 s = mfma16(kf[ct][1], qf[rt][1], mfma16(kf[ct][0], qf[rt][0], z4));
        f32x4 bg = mfma16(gkf[ct][1], gqf[rt][1], mfma16(gkf[ct][0], gqf[rt][0], z4));
        bf16x4 pk;
        float part = 0.f;
#pragma unroll
        for (int i = 0; i < 4; i++) {
          float bb = bg[i];
          float scl = bb > 0.f ? pos2 : neg2;
          float p = __builtin_amdgcn_exp2f(fmaf(bb, scl, s[i] * sc2));
          part += p;
          pk[i] = (__bf16)p;
        }
        lrowq[rt] += part;
        *(bf16x4*)&Ps[w][swz(rt * 16 + l15, ct * 16 + quad * 4)] = pk;
      }
    // PV: A = P[n][m] (b128 from swizzled per-wave tile), B = V^T[d][m]
    bf16x8 pf[2][2], vf[4][2];
#pragma unroll
    for (int rt = 0; rt < 2; rt++)
#pragma unroll
      for (int ms = 0; ms < 2; ms++)
        pf[rt][ms] = *(const bf16x8*)&Ps[w][swz(rt * 16 + l15, ms * 32 + quad * 8)];
#pragma unroll
    for (int dt = 0; dt < 4; dt++)
#pragma unroll
      for (int ms = 0; ms < 2; ms++)
        vf[dt][ms] = *(const bf16x8*)&Vs[swz(dt * 16 + l15, ms * 32 + quad * 8)];
#pragma unroll
    for (int rt = 0; rt < 2; rt++)
#pragma unroll
      for (int dt = 0; dt < 4; dt++) {
        oacc[rt][dt] = mfma16(pf[rt][0], vf[dt][0], oacc[rt][dt]);
        oacc[rt][dt] = mfma16(pf[rt][1], vf[dt][1], oacc[rt][dt]);
      }
  }
  // lrowq[rt] holds this lane's quad-share for n = rt*16+l15: sum over quads,
  // then redistribute to the oacc layout (n = rt*16+quad*4+i) via bpermute.
  float ltot[2];
#pragma unroll
  for (int rt = 0; rt < 2; rt++) {
    float l = lrowq[rt];
    l += __shfl_xor(l, 16, 64);
    l += __shfl_xor(l, 32, 64);
    ltot[rt] = l;
  }
#pragma unroll
  for (int rt = 0; rt < 2; rt++)
#pragma unroll
    for (int i = 0; i < 4; i++) {
      float li = __shfl(ltot[rt], quad * 4 + i, 64);
      float inv = 1.f / li;
#pragma unroll
      for (int dt = 0; dt < 4; dt++)
        Out[(size_t)(b * NN + row0 + rt * 16 + quad * 4 + i) * DB + h * DHD + dt * 16 + l15] =
            (__bf16)(oacc[rt][dt][i] * inv);
    }
}

// ---------------------------------------------------------------------------
extern "C" void kernel_launch(void* const* d_in, const int* in_sizes, int n_in,
                              void* d_out, int out_size, void* d_ws, size_t ws_size,
                              hipStream_t stream) {
  const float* dataset = (const float*)d_in[0];
  const float* visual = (const float*)d_in[1];
  const float* wq_w = (const float*)d_in[2];
  const float* wq_b = (const float*)d_in[3];
  const float* wk_w = (const float*)d_in[4];
  const float* wk_b = (const float*)d_in[5];
  const float* wv_w = (const float*)d_in[6];
  const float* wv_b = (const float*)d_in[7];
  const float* wo_w = (const float*)d_in[8];
  const float* wo_b = (const float*)d_in[9];
  const float* gq_w = (const float*)d_in[10];
  const float* gq_b = (const float*)d_in[11];
  const float* gk_w = (const float*)d_in[12];
  const float* gk_b = (const float*)d_in[13];
  const float* pos_scale = (const float*)d_in[14];
  const float* neg_scale = (const float*)d_in[15];
  const float* als = (const float*)d_in[16];
  const float* ln_q_g = (const float*)d_in[17];
  const float* ln_q_b = (const float*)d_in[18];
  const float* ln_kv_g = (const float*)d_in[19];
  const float* ln_kv_b = (const float*)d_in[20];
  const float* ln_out_g = (const float*)d_in[21];
  const float* ln_out_b = (const float*)d_in[22];
  const float* ff1_w = (const float*)d_in[23];
  const float* ff1_b = (const float*)d_in[24];
  const float* ff2_w = (const float*)d_in[25];
  const float* ff2_b = (const float*)d_in[26];

  char* ws = (char*)d_ws;
  size_t off = 0;
  auto alloc = [&](size_t bytes) {
    size_t o = off;
    off += (bytes + 255) & ~(size_t)255;
    return o;
  };
  __bf16* t_wq = (__bf16*)(ws + alloc((size_t)1024 * 1024 * 2));
  __bf16* t_wk = (__bf16*)(ws + alloc((size_t)1024 * 1024 * 2));
  __bf16* t_wv = (__bf16*)(ws + alloc((size_t)1024 * 1024 * 2));
  __bf16* t_wo = (__bf16*)(ws + alloc((size_t)1024 * 1024 * 2));
  __bf16* t_ff1 = (__bf16*)(ws + alloc((size_t)2048 * 1024 * 2));
  __bf16* t_ff2 = (__bf16*)(ws + alloc((size_t)1024 * 2048 * 2));
  __bf16* t_gq = (__bf16*)(ws + alloc((size_t)64 * 1024 * 2));
  __bf16* t_gk = (__bf16*)(ws + alloc((size_t)64 * 1024 * 2));
  size_t qin_off = alloc((size_t)4096 * 1024 * 2);   // aliased as hbuf later
  size_t kvin_off = alloc((size_t)8192 * 1024 * 2);  // aliased as out1(f32) later
  __bf16* qin = (__bf16*)(ws + qin_off);
  __bf16* kvin = (__bf16*)(ws + kvin_off);
  __bf16* geoq = (__bf16*)(ws + alloc((size_t)4096 * 64 * 2));
  __bf16* geok = (__bf16*)(ws + alloc((size_t)8192 * 64 * 2));
  float* sums = (float*)(ws + alloc((size_t)2 * 4 * 64 * 4));
  __bf16* qb = (__bf16*)(ws + alloc((size_t)4096 * 1024 * 2));
  __bf16* kb = (__bf16*)(ws + alloc((size_t)8192 * 1024 * 2));
  __bf16* vtb = (__bf16*)(ws + alloc((size_t)1024 * 8192 * 2));  // V^T [ch][tok]
  __bf16* attn = (__bf16*)(ws + alloc((size_t)4096 * 1024 * 2));
  __bf16* ffh = (__bf16*)(ws + alloc((size_t)4096 * 2048 * 2));
  // aliases (lifetimes disjoint):
  float* out1 = (float*)(ws + kvin_off);   // f32 [4096,1024] over kv_in
  __bf16* hbuf = (__bf16*)(ws + qin_off);  // bf16 [4096,1024] over q_in
  float* outp = (float*)d_out;

  dim3 blk(256);
  // 1. all weight transposes in one launch
  k_transpose_all<<<8320, blk, 0, stream>>>(wq_w, wk_w, wv_w, wo_w, ff1_w, ff2_w,
                                            gq_w, gk_w, t_wq, t_wk, t_wv, t_wo,
                                            t_ff1, t_ff2, t_gq, t_gk);
  // 2. both input layernorms in one launch
  k_layernorm2<<<12288, blk, 0, stream>>>(dataset, ln_q_g, ln_q_b, qin,
                                          visual, ln_kv_g, ln_kv_b, kvin);
  // 3. geo path
  k_geo<<<384, blk, 0, stream>>>(qin, kvin, t_gq, t_gk, gq_b, gk_b, geoq, geok);
  hipMemsetAsync(sums, 0, 2 * 4 * 64 * 4, stream);
  k_l2sum<<<dim3(16, 4, 2), blk, 0, stream>>>(geoq, geok, sums);
  k_l2scale<<<dim3(16, 4), blk, 0, stream>>>(geok, sums);
  // 4. fused QKV projections
  k_qkv<<<1280, blk, 0, stream>>>(qin, kvin, t_wq, t_wk, t_wv,
                                  wq_b, wk_b, wv_b, qb, kb, vtb);
  // 5. flash attention (bias fused, S^T form)
  k_flash<<<512, blk, 0, stream>>>(qb, kb, vtb, geoq, geok, als,
                                   pos_scale, neg_scale, attn);
  // 6. output projection + residual, LN, FFN
  k_gemmn64<<<dim3(16, 32), blk, 0, stream>>>(attn, t_wo, wo_b, dataset, out1,
                                              1024, 1024);
  k_layernorm<<<4096, blk, 0, stream>>>(out1, ln_out_g, ln_out_b, hbuf);
  k_gemm128g<<<dim3(16, 32), blk, 0, stream>>>(hbuf, t_ff1, ff1_b, ffh,
                                               2048, 1024);
  k_gemmn64<<<dim3(16, 32), blk, 0, stream>>>(ffh, t_ff2, ff2_b, out1, outp,
                                              1024, 2048);
}